// Round 9
// baseline (293.724 us; speedup 1.0000x reference)
//
#include <hip/hip_runtime.h>
#include <hip/hip_bf16.h>

#define DIM 32
#define RPB 32             // receivers per bucket (r_local = 5 bits)
#define NBMAX 4096         // supports N <= 131072
#define NBLKP 128          // padded binning-block dim of hmatT rows
#define SORT_CAP 1024      // bucket edge cap; lambda=512, 22-sigma headroom
#define EPB (256 * 64)     // edges per binning block

#if defined(__has_builtin)
#if __has_builtin(__builtin_amdgcn_fdot2)
#define HAVE_FDOT2 1
#endif
#endif

typedef _Float16 h2v __attribute__((ext_vector_type(2)));

// ---------------- f16 / bf16 <-> fp32 helpers ------------------------------
__device__ __forceinline__ float b2f(ushort h) {
    union { float f; unsigned u; } u; u.u = ((unsigned)h) << 16; return u.f;
}
__device__ __forceinline__ float h2f(ushort u) {
    _Float16 h; __builtin_memcpy(&h, &u, 2); return (float)h;
}
__device__ __forceinline__ ushort f2h(float f) {
    _Float16 h = (_Float16)f; ushort u; __builtin_memcpy(&u, &h, 2); return u;
}

// dot of two packed-f16 pairs accumulated into fp32 (v_dot2_f32_f16)
__device__ __forceinline__ float dot2acc(unsigned a, unsigned b, float c) {
#ifdef HAVE_FDOT2
    h2v ha, hb; __builtin_memcpy(&ha, &a, 4); __builtin_memcpy(&hb, &b, 4);
    return __builtin_amdgcn_fdot2(ha, hb, c, false);
#else
    return fmaf(h2f((ushort)(a >> 16)), h2f((ushort)(b >> 16)),
           fmaf(h2f((ushort)(a & 0xffff)), h2f((ushort)(b & 0xffff)), c));
#endif
}

__device__ __forceinline__ int load_idx(const int* __restrict__ idx, size_t pos,
                                        int mode, int n) {
    int v = mode ? idx[2 * pos] : idx[pos];
    return v < 0 ? 0 : (v >= n ? n - 1 : v);
}
__device__ __forceinline__ float load_f(const void* p, size_t i, int bf) {
    return bf ? b2f(((const ushort*)p)[i]) : ((const float*)p)[i];
}

// ---------------------------------------------------------------------------
// K1 (fused): QKV GEMM for all blocks; first nblk blocks ALSO histogram their
// EPB edge range into hmatT[bucket][block] + global bcount.
// Per-block probes: bf (x dtype) and mode (idx layout) via 64-lane ballots on
// L2-cached header words — removes the separate probe kernel.
// Q is pre-scaled by 1/sqrt(32).
// ---------------------------------------------------------------------------
__global__ void __launch_bounds__(256)
qkv_count_kernel(const void* __restrict__ x_, const void* __restrict__ Wq_,
                 const void* __restrict__ Wk_, const void* __restrict__ Wv_,
                 const int* __restrict__ idx, int N, int E, int nb, int nblk,
                 ushort* __restrict__ Q, ushort* __restrict__ KV,
                 int* __restrict__ bcount, int* __restrict__ hmatT) {
    __shared__ float sW[3][DIM * DIM];
    __shared__ float sx[8][DIM];
    __shared__ int h[NBMAX];
    __shared__ int sBf, sMode;

    const int tid = threadIdx.x;
    if (tid < 64) {
        int e = (((const ushort*)x_)[2 * tid] >> 7) & 0xFF;
        unsigned long long bb = __ballot(e >= 100 && e <= 135);
        unsigned long long mm = __ballot(idx[2 * tid + 1] != 0);
        if (tid == 0) { sBf = (__popcll(bb) >= 56); sMode = (mm == 0ULL); }
    }
    __syncthreads();
    const int bf = sBf, mode = sMode;

    if (blockIdx.x < nblk) {                 // fused bin-count phase
        for (int i = tid; i < nb; i += 256) h[i] = 0;
        __syncthreads();
        const int base_e = blockIdx.x * EPB;
#pragma unroll 4
        for (int k = 0; k < 64; ++k) {
            const int e = base_e + k * 256 + tid;
            if (e < E) {
                const int r = load_idx(idx, (size_t)E + e, mode, N);
                atomicAdd(&h[r >> 5], 1);
            }
        }
        __syncthreads();
        for (int i = tid; i < nb; i += 256) {
            const int v = h[i];
            hmatT[(size_t)i * NBLKP + blockIdx.x] = v;
            if (v) atomicAdd(&bcount[i], v);
        }
    }

    // ---- QKV GEMM ----
    for (int i = tid; i < DIM * DIM; i += 256) {
        sW[0][i] = load_f(Wq_, i, bf);
        sW[1][i] = load_f(Wk_, i, bf);
        sW[2][i] = load_f(Wv_, i, bf);
    }
    const int lr  = tid >> 5;
    const int d   = tid & 31;
    const int row = blockIdx.x * 8 + lr;
    if (row < N) sx[lr][d] = load_f(x_, (size_t)row * DIM + d, bf);
    __syncthreads();
    if (row >= N) return;

    float aq = 0.f, ak = 0.f, av = 0.f;
#pragma unroll
    for (int k = 0; k < DIM; ++k) {
        const float xk = sx[lr][k];
        aq += xk * sW[0][k * DIM + d];
        ak += xk * sW[1][k * DIM + d];
        av += xk * sW[2][k * DIM + d];
    }
    Q[(size_t)row * DIM + d]      = f2h(aq * 0.17677669529663687f);  // scale folded
    KV[(size_t)row * 64 + d]      = f2h(ak);
    KV[(size_t)row * 64 + 32 + d] = f2h(av);
}

// ---------------------------------------------------------------------------
// K2: 64 blocks x 1 wave; block handles `per` consecutive buckets. Computes
// bucket base from bcount prefix (coalesced), then per bucket scans its
// hmatT row (COALESCED: contiguous NBLKP ints) into global offsets; writes
// bbase.
// ---------------------------------------------------------------------------
__global__ void __launch_bounds__(64)
offsets_kernel(const int* __restrict__ bcount, int* __restrict__ bbase,
               int* __restrict__ hmatT, int nblk, int nb, int per) {
    const int lane = threadIdx.x;
    const int k0 = blockIdx.x * per;
    const int k1 = min(k0 + per, nb);
    int part = 0;
    for (int t = lane; t < k0; t += 64) part += bcount[t];
#pragma unroll
    for (int o = 1; o < 64; o <<= 1) part += __shfl_xor(part, o);
    int run = part;
    for (int k = k0; k < k1; ++k) {
        int* col = hmatT + (size_t)k * NBLKP;
        int carry = 0;
        for (int t0 = 0; t0 < nblk; t0 += 64) {
            const int t = t0 + lane;
            const int v = (t < nblk) ? col[t] : 0;
            int xx = v;
#pragma unroll
            for (int o = 1; o < 64; o <<= 1) {
                int y = __shfl_up(xx, o);
                if (lane >= o) xx += y;
            }
            if (t < nblk) col[t] = run + carry + xx - v;
            carry += __shfl(xx, 63);
        }
        if (lane == 0) bbase[k] = run;
        run += carry;
    }
}

// ---------------------------------------------------------------------------
// K3: single-pass placement; LDS cursors seeded from this block's hmatT slot.
// Packed edge = s | r_local<<17.
// ---------------------------------------------------------------------------
__global__ void __launch_bounds__(256)
bin_place_kernel(const int* __restrict__ idx, int E, int N, int nb,
                 const int* __restrict__ hmatT, int* __restrict__ bedges) {
    __shared__ int cur[NBMAX];
    __shared__ int sMode;
    const int tid = threadIdx.x;
    if (tid < 64) {
        unsigned long long mm = __ballot(idx[2 * tid + 1] != 0);
        if (tid == 0) sMode = (mm == 0ULL);
    }
    for (int i = tid; i < nb; i += 256) cur[i] = hmatT[(size_t)i * NBLKP + blockIdx.x];
    __syncthreads();
    const int mode = sMode;
    const int base_e = blockIdx.x * EPB;
#pragma unroll 4
    for (int k = 0; k < 64; ++k) {
        const int e = base_e + k * 256 + tid;
        if (e < E) {
            const int r = load_idx(idx, (size_t)E + e, mode, N);
            const int s = load_idx(idx, (size_t)e, mode, N);
            const int p = atomicAdd(&cur[r >> 5], 1);
            bedges[p] = s | ((r & 31) << 17);
        }
    }
}

// ---------------------------------------------------------------------------
// K4 (fused sort + aggregate): one block per 32-receiver bucket.
//  - LDS counting sort of the bucket's edges by r_local
//  - wave-per-receiver aggregation: 4 lanes/edge (16 edges/chunk), 16-B
//    dwordx4 K/V loads, v_dot2_f32_f16 dot, exp, register accumulation
//  - fused normalize + @Wo + residual epilogue
// ---------------------------------------------------------------------------
__global__ void __launch_bounds__(256)
sortagg_kernel(const ushort* __restrict__ Q, const ushort* __restrict__ KV,
               const int* __restrict__ bedges, const int* __restrict__ bcount,
               const int* __restrict__ bbase, const void* __restrict__ x_,
               const void* __restrict__ Wo_, int N, float* __restrict__ out) {
    __shared__ int   eL[SORT_CAP];
    __shared__ int   eS[SORT_CAP];
    __shared__ int   h[RPB], off[RPB], cur[RPB];
    __shared__ float accS[RPB][DIM + 1];
    __shared__ float Zs[RPB];
    __shared__ float sWo[DIM * DIM];
    __shared__ unsigned sQ[RPB * 16];
    __shared__ int sBf;

    const int tid = threadIdx.x;
    if (tid < 64) {
        int e = (((const ushort*)x_)[2 * tid] >> 7) & 0xFF;
        unsigned long long bb = __ballot(e >= 100 && e <= 135);
        if (tid == 0) sBf = (__popcll(bb) >= 56);
    }
    const int b   = blockIdx.x;
    const int r0  = b * RPB;
    const int nr  = min(RPB, N - r0);
    const int s0  = bbase[b];
    const int cnt = min(bcount[b], SORT_CAP);
    if (tid < RPB) h[tid] = 0;
    __syncthreads();
    const int bf = sBf;

    for (int i = tid; i < DIM * DIM; i += 256) sWo[i] = load_f(Wo_, i, bf);
    for (int i = tid; i < nr * 16; i += 256)
        sQ[i] = ((const unsigned*)(Q + (size_t)r0 * DIM))[i];
    for (int i = tid; i < cnt; i += 256) {
        const int e = bedges[s0 + i];
        eL[i] = e;
        atomicAdd(&h[(e >> 17) & 31], 1);
    }
    __syncthreads();
    if (tid == 0) {
        int a = 0;
#pragma unroll
        for (int k = 0; k < RPB; ++k) { off[k] = a; cur[k] = a; a += h[k]; }
    }
    __syncthreads();
    for (int i = tid; i < cnt; i += 256) {
        const int e = eL[i];
        const int p = atomicAdd(&cur[(e >> 17) & 31], 1);
        eS[p] = e & 0x1FFFF;
    }
    __syncthreads();

    const int w    = tid >> 6;
    const int lane = tid & 63;
    const int i16  = lane >> 2;   // edge sub-slot 0..15
    const int j    = lane & 3;    // channel group of 8 (j*8 .. j*8+7)

    for (int rl = w; rl < nr; rl += 4) {
        const int deg = h[rl];
        const int o0  = off[rl];
        const uint4 qw = *(const uint4*)&sQ[rl * 16 + j * 4];

        float a0 = 0.f, a1 = 0.f, a2 = 0.f, a3 = 0.f;
        float a4 = 0.f, a5 = 0.f, a6 = 0.f, a7 = 0.f, zs = 0.f;
        const int chunks = (deg + 15) >> 4;
        for (int cc = 0; cc < chunks; ++cc) {
            const int c   = cc * 16 + i16;
            const bool ok = (c < deg);
            const int  s  = eS[o0 + (ok ? c : deg - 1)];
            const ushort* kv = KV + (size_t)s * 64;
            const uint4 kw = *(const uint4*)(kv + j * 8);
            const uint4 vw = *(const uint4*)(kv + 32 + j * 8);

            float p = dot2acc(kw.x, qw.x, 0.f);
            p = dot2acc(kw.y, qw.y, p);
            p = dot2acc(kw.z, qw.z, p);
            p = dot2acc(kw.w, qw.w, p);
            p += __shfl_xor(p, 1);
            p += __shfl_xor(p, 2);          // full 32-ch dot (Q pre-scaled)

            p = fminf(fmaxf(p, -60.f), 60.f);
            const float a = ok ? __expf(p) : 0.f;

            a0 = fmaf(h2f((ushort)(vw.x & 0xffff)), a, a0);
            a1 = fmaf(h2f((ushort)(vw.x >> 16)),    a, a1);
            a2 = fmaf(h2f((ushort)(vw.y & 0xffff)), a, a2);
            a3 = fmaf(h2f((ushort)(vw.y >> 16)),    a, a3);
            a4 = fmaf(h2f((ushort)(vw.z & 0xffff)), a, a4);
            a5 = fmaf(h2f((ushort)(vw.z >> 16)),    a, a5);
            a6 = fmaf(h2f((ushort)(vw.w & 0xffff)), a, a6);
            a7 = fmaf(h2f((ushort)(vw.w >> 16)),    a, a7);
            zs += a;
        }
#pragma unroll
        for (int o = 4; o < 64; o <<= 1) {      // reduce across 16 edge slots
            a0 += __shfl_xor(a0, o); a1 += __shfl_xor(a1, o);
            a2 += __shfl_xor(a2, o); a3 += __shfl_xor(a3, o);
            a4 += __shfl_xor(a4, o); a5 += __shfl_xor(a5, o);
            a6 += __shfl_xor(a6, o); a7 += __shfl_xor(a7, o);
            zs += __shfl_xor(zs, o);
        }
        if (i16 == 0) {
            float* ar = accS[rl];
            ar[j * 8 + 0] = a0; ar[j * 8 + 1] = a1;
            ar[j * 8 + 2] = a2; ar[j * 8 + 3] = a3;
            ar[j * 8 + 4] = a4; ar[j * 8 + 5] = a5;
            ar[j * 8 + 6] = a6; ar[j * 8 + 7] = a7;
            if (j == 0) Zs[rl] = zs;
        }
    }
    __syncthreads();

    const int lr = tid >> 5;
    const int d  = tid & 31;
#pragma unroll
    for (int it = 0; it < RPB / 8; ++it) {
        const int rl = it * 8 + lr;
        if (rl < nr) {
            const float inv = 1.f / (Zs[rl] + 1e-6f);
            float o = 0.f;
#pragma unroll
            for (int k = 0; k < DIM; ++k) o += accS[rl][k] * sWo[k * DIM + d];
            const size_t oi = (size_t)(r0 + rl) * DIM + d;
            out[oi] = load_f(x_, oi, bf) + inv * o;
        }
    }
}

// ---------------------------------------------------------------------------
extern "C" void kernel_launch(void* const* d_in, const int* in_sizes, int n_in,
                              void* d_out, int out_size, void* d_ws, size_t ws_size,
                              hipStream_t stream) {
    const void* x   = d_in[0];
    const int*  idx = (const int*)d_in[1];
    const void* Wq  = d_in[2];
    const void* Wk  = d_in[3];
    const void* Wv  = d_in[4];
    const void* Wo  = d_in[5];
    float* out = (float*)d_out;           // fp32 reference output

    const int N = in_sizes[0] / DIM;      // 100000
    const int E = in_sizes[1] / 2;        // 1600000
    const int nb = (N + RPB - 1) / RPB;   // 3125 buckets
    const int nblk = (E + EPB - 1) / EPB; // 98 binning blocks (<= NBLKP)
    const int per = (nb + 63) / 64;       // buckets per offsets block
    const size_t N32 = (size_t)N * DIM;

    // Workspace (~28 MB): Q f16 | KV f16 | bedges | hmatT | bcount | bbase
    ushort* Q   = (ushort*)d_ws;
    ushort* KV  = Q + N32;                    // N * 64 halves (128 B/node)
    int* bedges = (int*)(KV + (size_t)N * 64);
    int* hmatT  = bedges + E;                 // NBMAX * NBLKP
    int* bcount = hmatT + (size_t)NBMAX * NBLKP;
    int* bbase  = bcount + NBMAX;

    hipMemsetAsync(bcount, 0, NBMAX * sizeof(int), stream);

    int qkv_grid = (N + 7) / 8;
    if (qkv_grid < nblk) qkv_grid = nblk;
    qkv_count_kernel<<<qkv_grid, 256, 0, stream>>>(x, Wq, Wk, Wv, idx, N, E,
                                                   nb, nblk, Q, KV, bcount, hmatT);

    offsets_kernel<<<64, 64, 0, stream>>>(bcount, bbase, hmatT, nblk, nb, per);

    bin_place_kernel<<<nblk, 256, 0, stream>>>(idx, E, N, nb, hmatT, bedges);

    sortagg_kernel<<<nb, 256, 0, stream>>>(Q, KV, bedges, bcount, bbase,
                                           x, Wo, N, out);
}

// Round 10
// 291.344 us; speedup vs baseline: 1.0082x; 1.0082x over previous
//
#include <hip/hip_runtime.h>
#include <hip/hip_bf16.h>

#define DIM 32
#define RPB 32              // receivers per agg block
#define RCR 512             // receivers per coarse region (r_local = 9 bits)
#define NCMAX 256           // max regions (N <= 131072)
#define CAPC 10640          // region capacity in ints (multiple of 16)
                            // mean E/nc=8163, +6sigma(542)+partial slack(128*15=1920)=10625
#define RING 32             // placeA ring depth per region
#define SENT 0xFFFFFFFFu

// ---------------- f16 / bf16 <-> fp32 helpers ------------------------------
__device__ __forceinline__ float b2f(ushort h) {
    union { float f; unsigned u; } u; u.u = ((unsigned)h) << 16; return u.f;
}
__device__ __forceinline__ float h2f(ushort u) {
    _Float16 h; __builtin_memcpy(&h, &u, 2); return (float)h;
}
__device__ __forceinline__ ushort f2h(float f) {
    _Float16 h = (_Float16)f; ushort u; __builtin_memcpy(&u, &h, 2); return u;
}

__device__ __forceinline__ int load_idx(const int* __restrict__ idx, size_t pos,
                                        int mode, int n) {
    int v = mode ? idx[2 * pos] : idx[pos];
    return v < 0 ? 0 : (v >= n ? n - 1 : v);
}
__device__ __forceinline__ float load_f(const void* p, size_t i, int bf) {
    return bf ? b2f(((const ushort*)p)[i]) : ((const float*)p)[i];
}

// ---------------------------------------------------------------------------
// K1: QKV GEMM (f16 outputs, Q pre-scaled by 1/sqrt(32), KV interleaved
// 128 B/node). Block 0 also initializes the region cursors (saves a launch).
// Inline ballot probes for x dtype.
// ---------------------------------------------------------------------------
__global__ void __launch_bounds__(256)
qkv_kernel(const void* __restrict__ x_, const void* __restrict__ Wq_,
           const void* __restrict__ Wk_, const void* __restrict__ Wv_,
           int N, int nc, ushort* __restrict__ Q, ushort* __restrict__ KV,
           unsigned* __restrict__ gcur) {
    __shared__ float sW[3][DIM * DIM];
    __shared__ float sx[8][DIM];
    __shared__ int sBf;

    const int tid = threadIdx.x;
    if (tid < 64) {
        int e = (((const ushort*)x_)[2 * tid] >> 7) & 0xFF;
        unsigned long long bb = __ballot(e >= 100 && e <= 135);
        if (tid == 0) sBf = (__popcll(bb) >= 56);
    }
    if (blockIdx.x == 0) {
        for (int i = tid; i < nc; i += 256) gcur[i] = (unsigned)i * CAPC;
    }
    __syncthreads();
    const int bf = sBf;

    for (int i = tid; i < DIM * DIM; i += 256) {
        sW[0][i] = load_f(Wq_, i, bf);
        sW[1][i] = load_f(Wk_, i, bf);
        sW[2][i] = load_f(Wv_, i, bf);
    }
    const int lr  = tid >> 5;
    const int d   = tid & 31;
    const int row = blockIdx.x * 8 + lr;
    if (row < N) sx[lr][d] = load_f(x_, (size_t)row * DIM + d, bf);
    __syncthreads();
    if (row >= N) return;

    float aq = 0.f, ak = 0.f, av = 0.f;
#pragma unroll
    for (int k = 0; k < DIM; ++k) {
        const float xk = sx[lr][k];
        aq += xk * sW[0][k * DIM + d];
        ak += xk * sW[1][k * DIM + d];
        av += xk * sW[2][k * DIM + d];
    }
    Q[(size_t)row * DIM + d]      = f2h(aq * 0.17677669529663687f);
    KV[(size_t)row * 64 + d]      = f2h(ak);
    KV[(size_t)row * 64 + 32 + d] = f2h(av);
}

// ---------------------------------------------------------------------------
// K2 (placeA): stream edges; buffer per coarse region in a 32-deep LDS ring;
// flush FULL 16-int (64 B) aligned chunks via one global atomic reservation.
// Every HBM write is a fully-covered line. Partials sentinel-padded.
// Packed edge = s | r_local<<17 (s<2^17, r_local<512).
// ---------------------------------------------------------------------------
__global__ void __launch_bounds__(256)
place_kernel(const int* __restrict__ idx, int E, int N, int nc,
             unsigned* __restrict__ gcur, unsigned* __restrict__ bedges) {
    __shared__ unsigned ring[NCMAX][RING];   // 32 KB
    __shared__ int wcnt[NCMAX], fcnt[NCMAX];
    __shared__ int sMode;

    const int tid = threadIdx.x;
    if (tid < 64) {
        unsigned long long mm = __ballot(idx[2 * tid + 1] != 0);
        if (tid == 0) sMode = (mm == 0ULL);
    }
    for (int i = tid; i < NCMAX; i += 256) { wcnt[i] = 0; fcnt[i] = 0; }
    __syncthreads();
    const int mode = sMode;

    const int per = (E + gridDim.x - 1) / gridDim.x;
    const int e0 = blockIdx.x * per;
    const int e1 = min(e0 + per, E);

    for (int eb = e0; eb < e1; eb += 256) {
        const int e = eb + tid;
        if (e < e1) {
            const int r = load_idx(idx, (size_t)E + e, mode, N);
            const int s = load_idx(idx, (size_t)e, mode, N);
            const int cb = r >> 9;
            const unsigned pkt = (unsigned)s | ((unsigned)(r & (RCR - 1)) << 17);
            const int p = atomicAdd(&wcnt[cb], 1);
            if (p - fcnt[cb] < RING) {
                ring[cb][p & (RING - 1)] = pkt;
            } else {
                // astronomically rare skew overflow: rollback + direct chunk
                atomicSub(&wcnt[cb], 1);
                unsigned dst = atomicAdd(&gcur[cb], 16);
                if (dst + 16 <= (unsigned)(cb + 1) * CAPC) {
                    bedges[dst] = pkt;
#pragma unroll
                    for (int q = 1; q < 16; ++q) bedges[dst + q] = SENT;
                }
            }
        }
        __syncthreads();
        if (tid < nc) {
            while (wcnt[tid] - fcnt[tid] >= 16) {
                unsigned dst = atomicAdd(&gcur[tid], 16);
                const int o = fcnt[tid] & (RING - 1);     // 0 or 16
                if (dst + 16 <= (unsigned)(tid + 1) * CAPC) {
                    uint4* dp = (uint4*)(bedges + dst);
                    const uint4* sp = (const uint4*)&ring[tid][o];
                    dp[0] = sp[0]; dp[1] = sp[1]; dp[2] = sp[2]; dp[3] = sp[3];
                }
                fcnt[tid] += 16;
            }
        }
        __syncthreads();
    }
    // drain partial chunk (sentinel-padded, still aligned)
    if (tid < nc) {
        const int k = wcnt[tid] - fcnt[tid];
        if (k > 0) {
            unsigned dst = atomicAdd(&gcur[tid], 16);
            if (dst + 16 <= (unsigned)(tid + 1) * CAPC) {
                const int o = fcnt[tid] & (RING - 1);
                for (int q = 0; q < 16; ++q)
                    bedges[dst + q] = (q < k) ? ring[tid][(o + q) & (RING - 1)] : SENT;
            }
        }
    }
}

// ---------------------------------------------------------------------------
// K3 (rsort): one block per region. Stage region in LDS, counting-sort by
// r_local (512 counters + block scan), write back in place (sender only)
// + per-receiver rbase/rcount CSR. Sentinels dropped.
// ---------------------------------------------------------------------------
__global__ void __launch_bounds__(1024)
rsort_kernel(unsigned* __restrict__ bedges, const unsigned* __restrict__ gcur,
             int* __restrict__ rbase, int* __restrict__ rcount) {
    __shared__ unsigned eL[CAPC];     // 42.6 KB
    __shared__ int cnt[RCR];
    __shared__ int wsum[8];

    const int tid = threadIdx.x;
    const int c = blockIdx.x;
    const unsigned s0 = (unsigned)c * CAPC;
    int m = (int)(gcur[c] - s0);
    if (m < 0) m = 0; if (m > CAPC) m = CAPC;

    if (tid < RCR) cnt[tid] = 0;
    __syncthreads();
    for (int i = tid; i < m; i += 1024) {
        const unsigned e = bedges[s0 + i];
        eL[i] = e;
        if (e != SENT) atomicAdd(&cnt[(e >> 17) & (RCR - 1)], 1);
    }
    __syncthreads();

    const int lane = tid & 63, w = tid >> 6;
    const int v = (tid < RCR) ? cnt[tid] : 0;
    int x = v;
#pragma unroll
    for (int o = 1; o < 64; o <<= 1) { int t = __shfl_up(x, o); if (lane >= o) x += t; }
    if (tid < RCR && lane == 63) wsum[w] = x;
    __syncthreads();
    if (tid == 0) {
        int a = 0;
#pragma unroll
        for (int k = 0; k < 8; ++k) { int t = wsum[k]; wsum[k] = a; a += t; }
    }
    __syncthreads();
    int excl = 0;
    if (tid < RCR) {
        excl = x - v + wsum[w];
        rbase[c * RCR + tid]  = (int)s0 + excl;
        rcount[c * RCR + tid] = v;
    }
    __syncthreads();
    if (tid < RCR) cnt[tid] = (int)s0 + excl;
    __syncthreads();
    for (int i = tid; i < m; i += 1024) {
        const unsigned e = eL[i];
        if (e != SENT) {
            const int p = atomicAdd(&cnt[(e >> 17) & (RCR - 1)], 1);
            bedges[p] = e & 0x1FFFF;
        }
    }
}

// ---------------------------------------------------------------------------
// K4 (agg): wave-per-receiver over CSR; round-8 inner loop (8 lanes/edge,
// ushort4 8B loads, fmaf-h2f dot, Q pre-scaled). Fused normalize+@Wo+residual.
// ---------------------------------------------------------------------------
__global__ void __launch_bounds__(256)
agg_kernel(const ushort* __restrict__ Q, const ushort* __restrict__ KV,
           const unsigned* __restrict__ bedges, const int* __restrict__ rbase,
           const int* __restrict__ rcount, const void* __restrict__ x_,
           const void* __restrict__ Wo_, int N, float* __restrict__ out) {
    __shared__ float sWo[DIM * DIM];
    __shared__ float accS[RPB][DIM + 1];
    __shared__ float Zs[RPB];
    __shared__ unsigned sQ[RPB * 16];
    __shared__ int sBf;

    const int tid = threadIdx.x;
    if (tid < 64) {
        int e = (((const ushort*)x_)[2 * tid] >> 7) & 0xFF;
        unsigned long long bb = __ballot(e >= 100 && e <= 135);
        if (tid == 0) sBf = (__popcll(bb) >= 56);
    }
    const int r0 = blockIdx.x * RPB;
    const int nr = min(RPB, N - r0);
    __syncthreads();
    const int bf = sBf;

    for (int i = tid; i < DIM * DIM; i += 256) sWo[i] = load_f(Wo_, i, bf);
    for (int i = tid; i < nr * 16; i += 256)
        sQ[i] = ((const unsigned*)(Q + (size_t)r0 * DIM))[i];
    __syncthreads();

    const int w    = tid >> 6;
    const int lane = tid & 63;
    const int i8   = lane >> 3;   // edge sub-slot 0..7
    const int j    = lane & 7;    // channel group 0..7

    for (int rl = w; rl < nr; rl += 4) {
        const int r   = r0 + rl;
        const int deg = rcount[r];
        const int o0  = rbase[r];
        const ushort4 qh = *(const ushort4*)((const ushort*)sQ + rl * DIM + j * 4);
        const float q0 = h2f(qh.x), q1 = h2f(qh.y), q2 = h2f(qh.z), q3 = h2f(qh.w);

        float ax = 0.f, ay = 0.f, az = 0.f, aw = 0.f, zs = 0.f;
        const int chunks = (deg + 7) >> 3;
        for (int cc = 0; cc < chunks; ++cc) {
            const int c   = cc * 8 + i8;
            const bool ok = (c < deg);
            const int  s  = (int)bedges[o0 + (ok ? c : deg - 1)];
            const ushort* kv = KV + (size_t)s * 64;

            const ushort4 kh = *(const ushort4*)(kv + j * 4);
            float p = h2f(kh.x) * q0;
            p = fmaf(h2f(kh.y), q1, p);
            p = fmaf(h2f(kh.z), q2, p);
            p = fmaf(h2f(kh.w), q3, p);
            p += __shfl_xor(p, 1);
            p += __shfl_xor(p, 2);
            p += __shfl_xor(p, 4);          // full 32-ch dot (Q pre-scaled)

            p = fminf(fmaxf(p, -60.f), 60.f);
            const float a = ok ? __expf(p) : 0.f;

            const ushort4 vh = *(const ushort4*)(kv + 32 + j * 4);
            ax = fmaf(h2f(vh.x), a, ax);
            ay = fmaf(h2f(vh.y), a, ay);
            az = fmaf(h2f(vh.z), a, az);
            aw = fmaf(h2f(vh.w), a, aw);
            zs += a;
        }
#pragma unroll
        for (int o = 8; o < 64; o <<= 1) {
            ax += __shfl_xor(ax, o); ay += __shfl_xor(ay, o);
            az += __shfl_xor(az, o); aw += __shfl_xor(aw, o);
            zs += __shfl_xor(zs, o);
        }
        if (i8 == 0) {
            float* ar = accS[rl];
            ar[j * 4 + 0] = ax; ar[j * 4 + 1] = ay;
            ar[j * 4 + 2] = az; ar[j * 4 + 3] = aw;
            if (j == 0) Zs[rl] = zs;
        }
    }
    __syncthreads();

    const int lr = tid >> 5;
    const int d  = tid & 31;
#pragma unroll
    for (int it = 0; it < RPB / 8; ++it) {
        const int rl = it * 8 + lr;
        if (rl < nr) {
            const float inv = 1.f / (Zs[rl] + 1e-6f);
            float o = 0.f;
#pragma unroll
            for (int k = 0; k < DIM; ++k) o += accS[rl][k] * sWo[k * DIM + d];
            const size_t oi = (size_t)(r0 + rl) * DIM + d;
            out[oi] = load_f(x_, oi, bf) + inv * o;
        }
    }
}

// ---------------------------------------------------------------------------
extern "C" void kernel_launch(void* const* d_in, const int* in_sizes, int n_in,
                              void* d_out, int out_size, void* d_ws, size_t ws_size,
                              hipStream_t stream) {
    const void* x   = d_in[0];
    const int*  idx = (const int*)d_in[1];
    const void* Wq  = d_in[2];
    const void* Wk  = d_in[3];
    const void* Wv  = d_in[4];
    const void* Wo  = d_in[5];
    float* out = (float*)d_out;           // fp32 reference output

    const int N = in_sizes[0] / DIM;      // 100000
    const int E = in_sizes[1] / 2;        // 1600000
    const int nc = (N + RCR - 1) / RCR;   // 196 coarse regions
    const size_t N32 = (size_t)N * DIM;

    // Workspace (~28.4 MB): Q f16 | KV f16 | bedges | gcur | rbase | rcount
    ushort*   Q      = (ushort*)d_ws;
    ushort*   KV     = Q + N32;                    // N * 64 halves
    unsigned* bedges = (unsigned*)(KV + (size_t)N * 64);   // nc * CAPC
    unsigned* gcur   = bedges + (size_t)nc * CAPC;
    int*      rbase  = (int*)(gcur + NCMAX);
    int*      rcount = rbase + (size_t)nc * RCR;

    qkv_kernel<<<(N + 7) / 8, 256, 0, stream>>>(x, Wq, Wk, Wv, N, nc, Q, KV, gcur);
    place_kernel<<<128, 256, 0, stream>>>(idx, E, N, nc, gcur, bedges);
    rsort_kernel<<<nc, 1024, 0, stream>>>(bedges, gcur, rbase, rcount);
    agg_kernel<<<(N + RPB - 1) / RPB, 256, 0, stream>>>(Q, KV, bedges, rbase,
                                                        rcount, x, Wo, N, out);
}

// Round 11
// 228.310 us; speedup vs baseline: 1.2865x; 1.2761x over previous
//
#include <hip/hip_runtime.h>
#include <hip/hip_bf16.h>

#define DIM 32
#define RPB 32              // receivers per agg block
#define RCR 512             // receivers per coarse region (r_local = 9 bits)
#define NCMAX 256           // max regions (N <= 131072)
#define CAPC 9216           // region capacity (ints); mean 8192, +11 sigma
#define PBLK 256            // place grid

// ---------------- f16 / bf16 <-> fp32 helpers ------------------------------
__device__ __forceinline__ float b2f(ushort h) {
    union { float f; unsigned u; } u; u.u = ((unsigned)h) << 16; return u.f;
}
__device__ __forceinline__ float h2f(ushort u) {
    _Float16 h; __builtin_memcpy(&h, &u, 2); return (float)h;
}
__device__ __forceinline__ ushort f2h(float f) {
    _Float16 h = (_Float16)f; ushort u; __builtin_memcpy(&u, &h, 2); return u;
}

__device__ __forceinline__ int load_idx(const int* __restrict__ idx, size_t pos,
                                        int mode, int n) {
    int v = mode ? idx[2 * pos] : idx[pos];
    return v < 0 ? 0 : (v >= n ? n - 1 : v);
}
__device__ __forceinline__ float load_f(const void* p, size_t i, int bf) {
    return bf ? b2f(((const ushort*)p)[i]) : ((const float*)p)[i];
}

// ---------------------------------------------------------------------------
// K1: QKV GEMM (f16 outputs, Q pre-scaled by 1/sqrt(32), KV interleaved
// 128 B/node). Block 0 initializes region cursors. Inline dtype probe.
// ---------------------------------------------------------------------------
__global__ void __launch_bounds__(256)
qkv_kernel(const void* __restrict__ x_, const void* __restrict__ Wq_,
           const void* __restrict__ Wk_, const void* __restrict__ Wv_,
           int N, int nc, ushort* __restrict__ Q, ushort* __restrict__ KV,
           unsigned* __restrict__ gcur) {
    __shared__ float sW[3][DIM * DIM];
    __shared__ float sx[8][DIM];
    __shared__ int sBf;

    const int tid = threadIdx.x;
    if (tid < 64) {
        int e = (((const ushort*)x_)[2 * tid] >> 7) & 0xFF;
        unsigned long long bb = __ballot(e >= 100 && e <= 135);
        if (tid == 0) sBf = (__popcll(bb) >= 56);
    }
    if (blockIdx.x == 0) {
        for (int i = tid; i < nc; i += 256) gcur[i] = (unsigned)i * CAPC;
    }
    __syncthreads();
    const int bf = sBf;

    for (int i = tid; i < DIM * DIM; i += 256) {
        sW[0][i] = load_f(Wq_, i, bf);
        sW[1][i] = load_f(Wk_, i, bf);
        sW[2][i] = load_f(Wv_, i, bf);
    }
    const int lr  = tid >> 5;
    const int d   = tid & 31;
    const int row = blockIdx.x * 8 + lr;
    if (row < N) sx[lr][d] = load_f(x_, (size_t)row * DIM + d, bf);
    __syncthreads();
    if (row >= N) return;

    float aq = 0.f, ak = 0.f, av = 0.f;
#pragma unroll
    for (int k = 0; k < DIM; ++k) {
        const float xk = sx[lr][k];
        aq += xk * sW[0][k * DIM + d];
        ak += xk * sW[1][k * DIM + d];
        av += xk * sW[2][k * DIM + d];
    }
    Q[(size_t)row * DIM + d]      = f2h(aq * 0.17677669529663687f);
    KV[(size_t)row * 64 + d]      = f2h(ak);
    KV[(size_t)row * 64 + 32 + d] = f2h(av);
}

// ---------------------------------------------------------------------------
// K2 (place): two-pass hist + place into fixed-capacity regions.
// Pass 1: LDS histogram of this block's edge slice over nc regions.
// One global atomicAdd per (block, region) reserves the output range.
// Pass 2: re-read slice (L2-hot), scatter via LDS cursors. Runs per region
// ~ slice/nc ~= 32 consecutive ints -> negligible write amplification.
// Packed edge = s | r_local<<17.
// ---------------------------------------------------------------------------
__global__ void __launch_bounds__(256)
place_kernel(const int* __restrict__ idx, int E, int N, int nc,
             unsigned* __restrict__ gcur, unsigned* __restrict__ bedges) {
    __shared__ int h[NCMAX];
    __shared__ int goff[NCMAX];
    __shared__ int sMode;

    const int tid = threadIdx.x;
    if (tid < 64) {
        unsigned long long mm = __ballot(idx[2 * tid + 1] != 0);
        if (tid == 0) sMode = (mm == 0ULL);
    }
    for (int i = tid; i < nc; i += 256) h[i] = 0;
    __syncthreads();
    const int mode = sMode;

    const int per = (E + gridDim.x - 1) / gridDim.x;
    const int e0 = blockIdx.x * per;
    const int e1 = min(e0 + per, E);

    for (int e = e0 + tid; e < e1; e += 256) {
        const int r = load_idx(idx, (size_t)E + e, mode, N);
        atomicAdd(&h[r >> 9], 1);
    }
    __syncthreads();
    for (int i = tid; i < nc; i += 256) {
        const int v = h[i];
        goff[i] = v ? (int)atomicAdd(&gcur[i], (unsigned)v) : 0;
        h[i] = 0;                      // reuse as local cursor
    }
    __syncthreads();
    for (int e = e0 + tid; e < e1; e += 256) {
        const int r = load_idx(idx, (size_t)E + e, mode, N);
        const int s = load_idx(idx, (size_t)e, mode, N);
        const int cb = r >> 9;
        const int p = goff[cb] + atomicAdd(&h[cb], 1);
        if (p < (cb + 1) * CAPC)       // overflow guard (11-sigma headroom)
            bedges[p] = (unsigned)s | ((unsigned)(r & (RCR - 1)) << 17);
    }
}

// ---------------------------------------------------------------------------
// K3 (rsort): one 1024-thread block per region. Stage region in LDS,
// counting-sort by r_local (512 counters + block scan), write back sender-only
// + per-receiver rbase/rcount CSR (indexed by global receiver id).
// ---------------------------------------------------------------------------
__global__ void __launch_bounds__(1024)
rsort_kernel(unsigned* __restrict__ bedges, const unsigned* __restrict__ gcur,
             int* __restrict__ rbase, int* __restrict__ rcount) {
    __shared__ unsigned eL[CAPC];     // 36.9 KB
    __shared__ int cnt[RCR];
    __shared__ int wsum[8];

    const int tid = threadIdx.x;
    const int c = blockIdx.x;
    const unsigned s0 = (unsigned)c * CAPC;
    int m = (int)(gcur[c] - s0);
    if (m < 0) m = 0; if (m > CAPC) m = CAPC;

    if (tid < RCR) cnt[tid] = 0;
    __syncthreads();
    for (int i = tid; i < m; i += 1024) {
        const unsigned e = bedges[s0 + i];
        eL[i] = e;
        atomicAdd(&cnt[(e >> 17) & (RCR - 1)], 1);
    }
    __syncthreads();

    const int lane = tid & 63, w = tid >> 6;
    const int v = (tid < RCR) ? cnt[tid] : 0;
    int x = v;
#pragma unroll
    for (int o = 1; o < 64; o <<= 1) { int t = __shfl_up(x, o); if (lane >= o) x += t; }
    if (tid < RCR && lane == 63) wsum[w] = x;
    __syncthreads();
    if (tid == 0) {
        int a = 0;
#pragma unroll
        for (int k = 0; k < 8; ++k) { int t = wsum[k]; wsum[k] = a; a += t; }
    }
    __syncthreads();
    int excl = 0;
    if (tid < RCR) {
        excl = x - v + wsum[w];
        rbase[c * RCR + tid]  = (int)s0 + excl;
        rcount[c * RCR + tid] = v;
    }
    __syncthreads();
    if (tid < RCR) cnt[tid] = (int)s0 + excl;
    __syncthreads();
    for (int i = tid; i < m; i += 1024) {
        const unsigned e = eL[i];
        const int p = atomicAdd(&cnt[(e >> 17) & (RCR - 1)], 1);
        bedges[p] = e & 0x1FFFF;
    }
}

// ---------------------------------------------------------------------------
// K4 (agg): wave-per-receiver over CSR; round-8 inner loop (8 lanes/edge,
// ushort4 8B loads, fmaf-h2f dot, Q pre-scaled). Fused normalize+@Wo+residual.
// ---------------------------------------------------------------------------
__global__ void __launch_bounds__(256)
agg_kernel(const ushort* __restrict__ Q, const ushort* __restrict__ KV,
           const unsigned* __restrict__ bedges, const int* __restrict__ rbase,
           const int* __restrict__ rcount, const void* __restrict__ x_,
           const void* __restrict__ Wo_, int N, float* __restrict__ out) {
    __shared__ float sWo[DIM * DIM];
    __shared__ float accS[RPB][DIM + 1];
    __shared__ float Zs[RPB];
    __shared__ unsigned sQ[RPB * 16];
    __shared__ int sBf;

    const int tid = threadIdx.x;
    if (tid < 64) {
        int e = (((const ushort*)x_)[2 * tid] >> 7) & 0xFF;
        unsigned long long bb = __ballot(e >= 100 && e <= 135);
        if (tid == 0) sBf = (__popcll(bb) >= 56);
    }
    const int r0 = blockIdx.x * RPB;
    const int nr = min(RPB, N - r0);
    __syncthreads();
    const int bf = sBf;

    for (int i = tid; i < DIM * DIM; i += 256) sWo[i] = load_f(Wo_, i, bf);
    for (int i = tid; i < nr * 16; i += 256)
        sQ[i] = ((const unsigned*)(Q + (size_t)r0 * DIM))[i];
    __syncthreads();

    const int w    = tid >> 6;
    const int lane = tid & 63;
    const int i8   = lane >> 3;   // edge sub-slot 0..7
    const int j    = lane & 7;    // channel group 0..7

    for (int rl = w; rl < nr; rl += 4) {
        const int r   = r0 + rl;
        const int deg = rcount[r];
        const int o0  = rbase[r];
        const ushort4 qh = *(const ushort4*)((const ushort*)sQ + rl * DIM + j * 4);
        const float q0 = h2f(qh.x), q1 = h2f(qh.y), q2 = h2f(qh.z), q3 = h2f(qh.w);

        float ax = 0.f, ay = 0.f, az = 0.f, aw = 0.f, zs = 0.f;
        const int chunks = (deg + 7) >> 3;
        for (int cc = 0; cc < chunks; ++cc) {
            const int c   = cc * 8 + i8;
            const bool ok = (c < deg);
            const int  s  = (int)bedges[o0 + (ok ? c : deg - 1)];
            const ushort* kv = KV + (size_t)s * 64;

            const ushort4 kh = *(const ushort4*)(kv + j * 4);
            float p = h2f(kh.x) * q0;
            p = fmaf(h2f(kh.y), q1, p);
            p = fmaf(h2f(kh.z), q2, p);
            p = fmaf(h2f(kh.w), q3, p);
            p += __shfl_xor(p, 1);
            p += __shfl_xor(p, 2);
            p += __shfl_xor(p, 4);          // full 32-ch dot (Q pre-scaled)

            p = fminf(fmaxf(p, -60.f), 60.f);
            const float a = ok ? __expf(p) : 0.f;

            const ushort4 vh = *(const ushort4*)(kv + 32 + j * 4);
            ax = fmaf(h2f(vh.x), a, ax);
            ay = fmaf(h2f(vh.y), a, ay);
            az = fmaf(h2f(vh.z), a, az);
            aw = fmaf(h2f(vh.w), a, aw);
            zs += a;
        }
#pragma unroll
        for (int o = 8; o < 64; o <<= 1) {
            ax += __shfl_xor(ax, o); ay += __shfl_xor(ay, o);
            az += __shfl_xor(az, o); aw += __shfl_xor(aw, o);
            zs += __shfl_xor(zs, o);
        }
        if (i8 == 0) {
            float* ar = accS[rl];
            ar[j * 4 + 0] = ax; ar[j * 4 + 1] = ay;
            ar[j * 4 + 2] = az; ar[j * 4 + 3] = aw;
            if (j == 0) Zs[rl] = zs;
        }
    }
    __syncthreads();

    const int lr = tid >> 5;
    const int d  = tid & 31;
#pragma unroll
    for (int it = 0; it < RPB / 8; ++it) {
        const int rl = it * 8 + lr;
        if (rl < nr) {
            const float inv = 1.f / (Zs[rl] + 1e-6f);
            float o = 0.f;
#pragma unroll
            for (int k = 0; k < DIM; ++k) o += accS[rl][k] * sWo[k * DIM + d];
            const size_t oi = (size_t)(r0 + rl) * DIM + d;
            out[oi] = load_f(x_, oi, bf) + inv * o;
        }
    }
}

// ---------------------------------------------------------------------------
extern "C" void kernel_launch(void* const* d_in, const int* in_sizes, int n_in,
                              void* d_out, int out_size, void* d_ws, size_t ws_size,
                              hipStream_t stream) {
    const void* x   = d_in[0];
    const int*  idx = (const int*)d_in[1];
    const void* Wq  = d_in[2];
    const void* Wk  = d_in[3];
    const void* Wv  = d_in[4];
    const void* Wo  = d_in[5];
    float* out = (float*)d_out;           // fp32 reference output

    const int N = in_sizes[0] / DIM;      // 100000
    const int E = in_sizes[1] / 2;        // 1600000
    const int nc = (N + RCR - 1) / RCR;   // 196 coarse regions
    const size_t N32 = (size_t)N * DIM;

    // Workspace (~28 MB): Q f16 | KV f16 | bedges | gcur | rbase | rcount
    ushort*   Q      = (ushort*)d_ws;
    ushort*   KV     = Q + N32;                          // N * 64 halves
    unsigned* bedges = (unsigned*)(KV + (size_t)N * 64); // nc * CAPC
    unsigned* gcur   = bedges + (size_t)nc * CAPC;
    int*      rbase  = (int*)(gcur + NCMAX);
    int*      rcount = rbase + (size_t)nc * RCR;

    qkv_kernel<<<(N + 7) / 8, 256, 0, stream>>>(x, Wq, Wk, Wv, N, nc, Q, KV, gcur);
    place_kernel<<<PBLK, 256, 0, stream>>>(idx, E, N, nc, gcur, bedges);
    rsort_kernel<<<nc, 1024, 0, stream>>>(bedges, gcur, rbase, rcount);
    agg_kernel<<<(N + RPB - 1) / RPB, 256, 0, stream>>>(Q, KV, bedges, rbase,
                                                        rcount, x, Wo, N, out);
}

// Round 12
// 212.287 us; speedup vs baseline: 1.3836x; 1.0755x over previous
//
#include <hip/hip_runtime.h>
#include <hip/hip_bf16.h>

#define DIM 32
#define RPB 32              // receivers per agg block
#define RCR 512             // receivers per coarse region (r_local = 9 bits)
#define NCMAX 256           // max regions (N <= 131072)
#define CAPC 9216           // region capacity (ints); mean 8192, +11 sigma
#define PBLK 256            // place grid

// ---------------- f16 / bf16 <-> fp32 helpers ------------------------------
__device__ __forceinline__ float b2f(ushort h) {
    union { float f; unsigned u; } u; u.u = ((unsigned)h) << 16; return u.f;
}
__device__ __forceinline__ float h2f(ushort u) {
    _Float16 h; __builtin_memcpy(&h, &u, 2); return (float)h;
}
__device__ __forceinline__ ushort f2h(float f) {
    _Float16 h = (_Float16)f; ushort u; __builtin_memcpy(&u, &h, 2); return u;
}

__device__ __forceinline__ int load_idx(const int* __restrict__ idx, size_t pos,
                                        int mode, int n) {
    int v = mode ? idx[2 * pos] : idx[pos];
    return v < 0 ? 0 : (v >= n ? n - 1 : v);
}
__device__ __forceinline__ float load_f(const void* p, size_t i, int bf) {
    return bf ? b2f(((const ushort*)p)[i]) : ((const float*)p)[i];
}

// ---------------------------------------------------------------------------
// K1: QKV GEMM (f16 outputs, Q pre-scaled by 1/sqrt(32), KV interleaved
// 128 B/node). Block 0 initializes region cursors. Inline dtype probe.
// ---------------------------------------------------------------------------
__global__ void __launch_bounds__(256)
qkv_kernel(const void* __restrict__ x_, const void* __restrict__ Wq_,
           const void* __restrict__ Wk_, const void* __restrict__ Wv_,
           int N, int nc, ushort* __restrict__ Q, ushort* __restrict__ KV,
           unsigned* __restrict__ gcur) {
    __shared__ float sW[3][DIM * DIM];
    __shared__ float sx[8][DIM];
    __shared__ int sBf;

    const int tid = threadIdx.x;
    if (tid < 64) {
        int e = (((const ushort*)x_)[2 * tid] >> 7) & 0xFF;
        unsigned long long bb = __ballot(e >= 100 && e <= 135);
        if (tid == 0) sBf = (__popcll(bb) >= 56);
    }
    if (blockIdx.x == 0) {
        for (int i = tid; i < nc; i += 256) gcur[i] = (unsigned)i * CAPC;
    }
    __syncthreads();
    const int bf = sBf;

    for (int i = tid; i < DIM * DIM; i += 256) {
        sW[0][i] = load_f(Wq_, i, bf);
        sW[1][i] = load_f(Wk_, i, bf);
        sW[2][i] = load_f(Wv_, i, bf);
    }
    const int lr  = tid >> 5;
    const int d   = tid & 31;
    const int row = blockIdx.x * 8 + lr;
    if (row < N) sx[lr][d] = load_f(x_, (size_t)row * DIM + d, bf);
    __syncthreads();
    if (row >= N) return;

    float aq = 0.f, ak = 0.f, av = 0.f;
#pragma unroll
    for (int k = 0; k < DIM; ++k) {
        const float xk = sx[lr][k];
        aq += xk * sW[0][k * DIM + d];
        ak += xk * sW[1][k * DIM + d];
        av += xk * sW[2][k * DIM + d];
    }
    Q[(size_t)row * DIM + d]      = f2h(aq * 0.17677669529663687f);
    KV[(size_t)row * 64 + d]      = f2h(ak);
    KV[(size_t)row * 64 + 32 + d] = f2h(av);
}

// ---------------------------------------------------------------------------
// K2 (place): two-pass hist + place into fixed-capacity regions.
// ---------------------------------------------------------------------------
__global__ void __launch_bounds__(256)
place_kernel(const int* __restrict__ idx, int E, int N, int nc,
             unsigned* __restrict__ gcur, unsigned* __restrict__ bedges) {
    __shared__ int h[NCMAX];
    __shared__ int goff[NCMAX];
    __shared__ int sMode;

    const int tid = threadIdx.x;
    if (tid < 64) {
        unsigned long long mm = __ballot(idx[2 * tid + 1] != 0);
        if (tid == 0) sMode = (mm == 0ULL);
    }
    for (int i = tid; i < nc; i += 256) h[i] = 0;
    __syncthreads();
    const int mode = sMode;

    const int per = (E + gridDim.x - 1) / gridDim.x;
    const int e0 = blockIdx.x * per;
    const int e1 = min(e0 + per, E);

    for (int e = e0 + tid; e < e1; e += 256) {
        const int r = load_idx(idx, (size_t)E + e, mode, N);
        atomicAdd(&h[r >> 9], 1);
    }
    __syncthreads();
    for (int i = tid; i < nc; i += 256) {
        const int v = h[i];
        goff[i] = v ? (int)atomicAdd(&gcur[i], (unsigned)v) : 0;
        h[i] = 0;                      // reuse as local cursor
    }
    __syncthreads();
    for (int e = e0 + tid; e < e1; e += 256) {
        const int r = load_idx(idx, (size_t)E + e, mode, N);
        const int s = load_idx(idx, (size_t)e, mode, N);
        const int cb = r >> 9;
        const int p = goff[cb] + atomicAdd(&h[cb], 1);
        if (p < (cb + 1) * CAPC)       // overflow guard (11-sigma headroom)
            bedges[p] = (unsigned)s | ((unsigned)(r & (RCR - 1)) << 17);
    }
}

// ---------------------------------------------------------------------------
// K3 (rsort): one 1024-thread block per region; LDS counting sort by r_local
// -> sender-only bedges + per-receiver rbase/rcount CSR.
// ---------------------------------------------------------------------------
__global__ void __launch_bounds__(1024)
rsort_kernel(unsigned* __restrict__ bedges, const unsigned* __restrict__ gcur,
             int* __restrict__ rbase, int* __restrict__ rcount) {
    __shared__ unsigned eL[CAPC];     // 36.9 KB
    __shared__ int cnt[RCR];
    __shared__ int wsum[8];

    const int tid = threadIdx.x;
    const int c = blockIdx.x;
    const unsigned s0 = (unsigned)c * CAPC;
    int m = (int)(gcur[c] - s0);
    if (m < 0) m = 0; if (m > CAPC) m = CAPC;

    if (tid < RCR) cnt[tid] = 0;
    __syncthreads();
    for (int i = tid; i < m; i += 1024) {
        const unsigned e = bedges[s0 + i];
        eL[i] = e;
        atomicAdd(&cnt[(e >> 17) & (RCR - 1)], 1);
    }
    __syncthreads();

    const int lane = tid & 63, w = tid >> 6;
    const int v = (tid < RCR) ? cnt[tid] : 0;
    int x = v;
#pragma unroll
    for (int o = 1; o < 64; o <<= 1) { int t = __shfl_up(x, o); if (lane >= o) x += t; }
    if (tid < RCR && lane == 63) wsum[w] = x;
    __syncthreads();
    if (tid == 0) {
        int a = 0;
#pragma unroll
        for (int k = 0; k < 8; ++k) { int t = wsum[k]; wsum[k] = a; a += t; }
    }
    __syncthreads();
    int excl = 0;
    if (tid < RCR) {
        excl = x - v + wsum[w];
        rbase[c * RCR + tid]  = (int)s0 + excl;
        rcount[c * RCR + tid] = v;
    }
    __syncthreads();
    if (tid < RCR) cnt[tid] = (int)s0 + excl;
    __syncthreads();
    for (int i = tid; i < m; i += 1024) {
        const unsigned e = eL[i];
        const int p = atomicAdd(&cnt[(e >> 17) & (RCR - 1)], 1);
        bedges[p] = e & 0x1FFFF;
    }
}

// ---------------------------------------------------------------------------
// K4 (agg): wave-per-receiver over CSR, chunk loop software-pipelined x2:
// both chunks' sender + K + V loads issued before any consumption -> ~2x
// loads in flight per wave (latency-bound kernel, VALUBusy 31% at x1).
// 8 lanes/edge, ushort4 8B loads, fmaf-h2f dot, Q pre-scaled.
// Fused normalize + @Wo + residual epilogue.
// ---------------------------------------------------------------------------
__global__ void __launch_bounds__(256)
agg_kernel(const ushort* __restrict__ Q, const ushort* __restrict__ KV,
           const unsigned* __restrict__ bedges, const int* __restrict__ rbase,
           const int* __restrict__ rcount, const void* __restrict__ x_,
           const void* __restrict__ Wo_, int N, float* __restrict__ out) {
    __shared__ float sWo[DIM * DIM];
    __shared__ float accS[RPB][DIM + 1];
    __shared__ float Zs[RPB];
    __shared__ unsigned sQ[RPB * 16];
    __shared__ int sBf;

    const int tid = threadIdx.x;
    if (tid < 64) {
        int e = (((const ushort*)x_)[2 * tid] >> 7) & 0xFF;
        unsigned long long bb = __ballot(e >= 100 && e <= 135);
        if (tid == 0) sBf = (__popcll(bb) >= 56);
    }
    const int r0 = blockIdx.x * RPB;
    const int nr = min(RPB, N - r0);
    __syncthreads();
    const int bf = sBf;

    for (int i = tid; i < DIM * DIM; i += 256) sWo[i] = load_f(Wo_, i, bf);
    for (int i = tid; i < nr * 16; i += 256)
        sQ[i] = ((const unsigned*)(Q + (size_t)r0 * DIM))[i];
    __syncthreads();

    const int w    = tid >> 6;
    const int lane = tid & 63;
    const int i8   = lane >> 3;   // edge sub-slot 0..7
    const int j    = lane & 7;    // channel group 0..7

    for (int rl = w; rl < nr; rl += 4) {
        const int r   = r0 + rl;
        const int deg = rcount[r];
        const int o0  = rbase[r];
        const ushort4 qh = *(const ushort4*)((const ushort*)sQ + rl * DIM + j * 4);
        const float q0 = h2f(qh.x), q1 = h2f(qh.y), q2 = h2f(qh.z), q3 = h2f(qh.w);

        float ax = 0.f, ay = 0.f, az = 0.f, aw = 0.f, zs = 0.f;
        const int chunks = (deg + 7) >> 3;
        const int dm1 = deg - 1;

        int cc = 0;
        for (; cc + 2 <= chunks; cc += 2) {
            const int c0 = cc * 8 + i8;
            const int c1 = c0 + 8;
            const bool ok0 = (c0 < deg);
            const bool ok1 = (c1 < deg);
            const int s0 = (int)bedges[o0 + (ok0 ? c0 : dm1)];
            const int s1 = (int)bedges[o0 + (ok1 ? c1 : dm1)];
            const ushort* kvA = KV + (size_t)s0 * 64;
            const ushort* kvB = KV + (size_t)s1 * 64;

            // issue all four 8-B loads before any use
            const ushort4 khA = *(const ushort4*)(kvA + j * 4);
            const ushort4 vhA = *(const ushort4*)(kvA + 32 + j * 4);
            const ushort4 khB = *(const ushort4*)(kvB + j * 4);
            const ushort4 vhB = *(const ushort4*)(kvB + 32 + j * 4);

            float pA = h2f(khA.x) * q0;
            float pB = h2f(khB.x) * q0;
            pA = fmaf(h2f(khA.y), q1, pA);  pB = fmaf(h2f(khB.y), q1, pB);
            pA = fmaf(h2f(khA.z), q2, pA);  pB = fmaf(h2f(khB.z), q2, pB);
            pA = fmaf(h2f(khA.w), q3, pA);  pB = fmaf(h2f(khB.w), q3, pB);

            pA += __shfl_xor(pA, 1);        pB += __shfl_xor(pB, 1);
            pA += __shfl_xor(pA, 2);        pB += __shfl_xor(pB, 2);
            pA += __shfl_xor(pA, 4);        pB += __shfl_xor(pB, 4);

            pA = fminf(fmaxf(pA, -60.f), 60.f);
            pB = fminf(fmaxf(pB, -60.f), 60.f);
            const float aA = ok0 ? __expf(pA) : 0.f;
            const float aB = ok1 ? __expf(pB) : 0.f;

            ax = fmaf(h2f(vhA.x), aA, ax);  ax = fmaf(h2f(vhB.x), aB, ax);
            ay = fmaf(h2f(vhA.y), aA, ay);  ay = fmaf(h2f(vhB.y), aB, ay);
            az = fmaf(h2f(vhA.z), aA, az);  az = fmaf(h2f(vhB.z), aB, az);
            aw = fmaf(h2f(vhA.w), aA, aw);  aw = fmaf(h2f(vhB.w), aB, aw);
            zs += aA + aB;
        }
        if (cc < chunks) {                   // odd remainder chunk
            const int c = cc * 8 + i8;
            const bool ok = (c < deg);
            const int s = (int)bedges[o0 + (ok ? c : dm1)];
            const ushort* kv = KV + (size_t)s * 64;
            const ushort4 kh = *(const ushort4*)(kv + j * 4);
            const ushort4 vh = *(const ushort4*)(kv + 32 + j * 4);

            float p = h2f(kh.x) * q0;
            p = fmaf(h2f(kh.y), q1, p);
            p = fmaf(h2f(kh.z), q2, p);
            p = fmaf(h2f(kh.w), q3, p);
            p += __shfl_xor(p, 1);
            p += __shfl_xor(p, 2);
            p += __shfl_xor(p, 4);
            p = fminf(fmaxf(p, -60.f), 60.f);
            const float a = ok ? __expf(p) : 0.f;

            ax = fmaf(h2f(vh.x), a, ax);
            ay = fmaf(h2f(vh.y), a, ay);
            az = fmaf(h2f(vh.z), a, az);
            aw = fmaf(h2f(vh.w), a, aw);
            zs += a;
        }
#pragma unroll
        for (int o = 8; o < 64; o <<= 1) {
            ax += __shfl_xor(ax, o); ay += __shfl_xor(ay, o);
            az += __shfl_xor(az, o); aw += __shfl_xor(aw, o);
            zs += __shfl_xor(zs, o);
        }
        if (i8 == 0) {
            float* ar = accS[rl];
            ar[j * 4 + 0] = ax; ar[j * 4 + 1] = ay;
            ar[j * 4 + 2] = az; ar[j * 4 + 3] = aw;
            if (j == 0) Zs[rl] = zs;
        }
    }
    __syncthreads();

    const int lr = tid >> 5;
    const int d  = tid & 31;
#pragma unroll
    for (int it = 0; it < RPB / 8; ++it) {
        const int rl = it * 8 + lr;
        if (rl < nr) {
            const float inv = 1.f / (Zs[rl] + 1e-6f);
            float o = 0.f;
#pragma unroll
            for (int k = 0; k < DIM; ++k) o += accS[rl][k] * sWo[k * DIM + d];
            const size_t oi = (size_t)(r0 + rl) * DIM + d;
            out[oi] = load_f(x_, oi, bf) + inv * o;
        }
    }
}

// ---------------------------------------------------------------------------
extern "C" void kernel_launch(void* const* d_in, const int* in_sizes, int n_in,
                              void* d_out, int out_size, void* d_ws, size_t ws_size,
                              hipStream_t stream) {
    const void* x   = d_in[0];
    const int*  idx = (const int*)d_in[1];
    const void* Wq  = d_in[2];
    const void* Wk  = d_in[3];
    const void* Wv  = d_in[4];
    const void* Wo  = d_in[5];
    float* out = (float*)d_out;           // fp32 reference output

    const int N = in_sizes[0] / DIM;      // 100000
    const int E = in_sizes[1] / 2;        // 1600000
    const int nc = (N + RCR - 1) / RCR;   // 196 coarse regions
    const size_t N32 = (size_t)N * DIM;

    // Workspace (~28 MB): Q f16 | KV f16 | bedges | gcur | rbase | rcount
    ushort*   Q      = (ushort*)d_ws;
    ushort*   KV     = Q + N32;                          // N * 64 halves
    unsigned* bedges = (unsigned*)(KV + (size_t)N * 64); // nc * CAPC
    unsigned* gcur   = bedges + (size_t)nc * CAPC;
    int*      rbase  = (int*)(gcur + NCMAX);
    int*      rcount = rbase + (size_t)nc * RCR;

    qkv_kernel<<<(N + 7) / 8, 256, 0, stream>>>(x, Wq, Wk, Wv, N, nc, Q, KV, gcur);
    place_kernel<<<PBLK, 256, 0, stream>>>(idx, E, N, nc, gcur, bedges);
    rsort_kernel<<<nc, 1024, 0, stream>>>(bedges, gcur, rbase, rcount);
    agg_kernel<<<(N + RPB - 1) / RPB, 256, 0, stream>>>(Q, KV, bedges, rbase,
                                                        rcount, x, Wo, N, out);
}